// Round 5
// baseline (1252.260 us; speedup 1.0000x reference)
//
#include <hip/hip_runtime.h>
#include <hip/hip_fp16.h>

#define G      160
#define G3     (G*G*G)
#define NRAYS  4096
#define SAMP   256
#define CK0    12
#define HID    128

// log(1/(1-0.01) - 1) = -log(99)
#define ACT_SHIFT (-4.59511985013459f)

#define FS 72     // feat slab row stride (halves); 144 B = 9*16 -> b128-aligned
#define HS 136    // h slab row stride (halves);   272 B = 17*16 -> b128-aligned
#define SLABH (64 * HS)   // per-wave slab (halves); feat (64*FS) overlays low part

typedef __attribute__((ext_vector_type(8))) _Float16 f16x8;
typedef __attribute__((ext_vector_type(4))) float    f32x4;

__device__ __forceinline__ unsigned pkrtz_u(float a, float b) {
    typedef __attribute__((ext_vector_type(2))) __fp16 fp16v2;
    union { fp16v2 h; unsigned u; } cv;
    cv.h = __builtin_amdgcn_cvt_pkrtz(a, b);
    return cv.u;
}

// ---------- weight prepack (parallel, fp16), B-frag order for mfma 16x16x32 ----------
// k = ks*32 + (l>>4)*8 + j, n = nt*16 + (l&15); element stored at [(f*64+l)*8+j]
#define W0PE (16 * 512)
#define W1PE (32 * 512)
#define W2PE (4 * 512)
__global__ __launch_bounds__(256) void pack_weights(
        const float* __restrict__ w0, const float* __restrict__ w1,
        const float* __restrict__ w2,
        unsigned short* __restrict__ w0p, unsigned short* __restrict__ w1p,
        unsigned short* __restrict__ w2p)
{
    int idx = blockIdx.x * 256 + threadIdx.x;
    if (idx < W0PE) {
        int f = idx >> 9, r = idx & 511, l = r >> 3, j = r & 7;
        int nt = f >> 1, ks = f & 1;
        int k = ks * 32 + ((l >> 4) << 3) + j;
        int nn = nt * 16 + (l & 15);
        w0p[idx] = (k < 39) ? __half_as_ushort(__float2half(w0[k * HID + nn]))
                            : (unsigned short)0;
    } else if (idx < W0PE + W1PE) {
        int m = idx - W0PE;
        int f = m >> 9, r = m & 511, l = r >> 3, j = r & 7;
        int nt = f >> 2, ks = f & 3;
        int k = ks * 32 + ((l >> 4) << 3) + j;
        int nn = nt * 16 + (l & 15);
        w1p[m] = __half_as_ushort(__float2half(w1[k * HID + nn]));
    } else if (idx < W0PE + W1PE + W2PE) {
        int m = idx - W0PE - W1PE;
        int ks = m >> 9, r = m & 511, l = r >> 3, j = r & 7;
        int k = ks * 32 + ((l >> 4) << 3) + j;
        int nn = l & 15;
        w2p[m] = (nn < 3) ? __half_as_ushort(__float2half(w2[k * 3 + nn]))
                          : (unsigned short)0;
    }
}

// ---------- main: one block per ray; 4 waves; fused fp32 gather + MFMA MLP ----------
__global__ __launch_bounds__(256) void dvgo_mfma(
        const float* __restrict__ pts,
        const float* __restrict__ viewdirs,
        const float* __restrict__ dgrid,
        const float* __restrict__ kgrid,
        const unsigned short* __restrict__ w0p,
        const unsigned short* __restrict__ w1p,
        const unsigned short* __restrict__ w2p,
        const float* __restrict__ b0, const float* __restrict__ b1,
        const float* __restrict__ b2,
        float* __restrict__ out)
{
    __shared__ __half s_mem[4 * SLABH];   // 69632 B
    __shared__ float  s_wgt[SAMP];
    __shared__ float  s_wave[4];
    __shared__ unsigned s_u[16];          // slots 2..15 = feat cols 12..39 (fp16 pairs)
    __shared__ float  s_out[4];

    const int n    = blockIdx.x;
    const int t    = threadIdx.x;
    const int lane = t & 63;
    const int wv   = t >> 6;
    const int wbase = wv << 6;
    const int c    = lane & 15;
    const int quad = lane >> 4;
    __half* slab = s_mem + wv * SLABH;
    const int lr = lane;                  // local row within slab

    if (t < 4) s_out[t] = 0.0f;

    // ---- view embedding: computed once per block (cols 12..39 are ray-uniform) ----
    if (t < 14) {
        float v0 = viewdirs[n * 3 + 0];
        float v1 = viewdirs[n * 3 + 1];
        float v2 = viewdirs[n * 3 + 2];
        float inv = rsqrtf(v0 * v0 + v1 * v1 + v2 * v2);
        float vd[3] = {v0 * inv, v1 * inv, v2 * inv};
        float fv[2];
#pragma unroll
        for (int e = 0; e < 2; e++) {
            int col = 12 + 2 * t + e;
            float f;
            if (col < 15)      f = vd[col - 12];
            else if (col < 27) { int s = col - 15; f = __sinf(vd[s >> 2] * (float)(1 << (s & 3))); }
            else if (col < 39) { int s = col - 27; f = __cosf(vd[s >> 2] * (float)(1 << (s & 3))); }
            else               f = 0.0f;
            fv[e] = f;
        }
        s_u[t + 2] = pkrtz_u(fv[0], fv[1]);
    }

    // ---- trilinear gather directly from fp32 grids ----
    const float* p = pts + ((size_t)n * SAMP + t) * 3;
    float pc[3] = {p[0], p[1], p[2]};
    int   i0[3];
    float fr[3];
#pragma unroll
    for (int d = 0; d < 3; d++) {
        float uu = (pc[d] + 1.0f) * 0.5f * (float)(G - 1);
        uu = fminf(fmaxf(uu, 0.0f), (float)(G - 1));
        int i = (int)floorf(uu);
        if (i > G - 2) i = G - 2;
        i0[d] = i;
        fr[d] = uu - (float)i;
    }

    float k0v[CK0];
#pragma unroll
    for (int ch = 0; ch < CK0; ch++) k0v[ch] = 0.0f;
    float dens = 0.0f;
    const float fz = fr[2], ifz = 1.0f - fz;

#pragma unroll
    for (int cx = 0; cx < 2; cx++) {
        float wx = cx ? fr[0] : 1.0f - fr[0];
#pragma unroll
        for (int cy = 0; cy < 2; cy++) {
            float wxy = wx * (cy ? fr[1] : 1.0f - fr[1]);
            int base = ((i0[0] + cx) * G + (i0[1] + cy)) * G + i0[2];
            float d0 = dgrid[base], d1 = dgrid[base + 1];
            dens += wxy * (d0 * ifz + d1 * fz);
#pragma unroll
            for (int ch = 0; ch < CK0; ch++) {
                float v0 = kgrid[(size_t)ch * G3 + base];
                float v1 = kgrid[(size_t)ch * G3 + base + 1];
                k0v[ch] += wxy * (v0 * ifz + v1 * fz);
            }
        }
    }

    // ---- alpha + wave-level cumprod scan ----
    float xs = dens + ACT_SHIFT;
    float sp = fmaxf(xs, 0.0f) + __logf(1.0f + __expf(-fabsf(xs)));
    float alpha = 1.0f - __expf(-sp * 0.5f);

    float xi = 1.0f - alpha;
#pragma unroll
    for (int off = 1; off < 64; off <<= 1) {
        float y = __shfl_up(xi, off);
        if (lane >= off) xi *= y;
    }
    if (lane == 63) s_wave[wv] = xi;

    __syncthreads();   // barrier A: s_u + s_wave visible

    // ---- exclusive transmittance -> per-sample weight (wave-local store) ----
    float prefix = 1.0f;
#pragma unroll
    for (int u = 0; u < 3; u++)
        if (u < wv) prefix *= s_wave[u];
    float xp = __shfl_up(xi, 1);
    float Texcl = prefix * ((lane == 0) ? 1.0f : xp);
    s_wgt[t] = alpha * Texcl;

    // ---- feat row -> slab (fp16) ----
    {
        uint4 q0, q1;
        q0.x = pkrtz_u(k0v[0],  k0v[1]);
        q0.y = pkrtz_u(k0v[2],  k0v[3]);
        q0.z = pkrtz_u(k0v[4],  k0v[5]);
        q0.w = pkrtz_u(k0v[6],  k0v[7]);
        q1.x = pkrtz_u(k0v[8],  k0v[9]);
        q1.y = pkrtz_u(k0v[10], k0v[11]);
        q1.z = s_u[2];
        q1.w = s_u[3];
        *reinterpret_cast<uint4*>(slab + lr * FS)     = q0;  // cols 0..7
        *reinterpret_cast<uint4*>(slab + lr * FS + 8) = q1;  // cols 8..15
        const uint4* uq = reinterpret_cast<const uint4*>(s_u);
        *reinterpret_cast<uint4*>(slab + lr * FS + 16) = uq[1];  // cols 16..23
        *reinterpret_cast<uint4*>(slab + lr * FS + 24) = uq[2];  // cols 24..31
        *reinterpret_cast<uint4*>(slab + lr * FS + 32) = uq[3];  // cols 32..39
        // cols 40..63 left garbage: never loaded (ks=1 frags zeroed for quad>0)
    }

    const f32x4 zf = {0.0f, 0.0f, 0.0f, 0.0f};
    const f16x8 zfrag = {};

    // ---- A1 fragments from feat (wave-private; DS pipe is in-order, no barrier) ----
    f16x8 a1[4][2];
#pragma unroll
    for (int mt = 0; mt < 4; mt++) {
        a1[mt][0] = *reinterpret_cast<const f16x8*>(slab + (mt * 16 + c) * FS + quad * 8);
        a1[mt][1] = zfrag;
        if (quad == 0)
            a1[mt][1] = *reinterpret_cast<const f16x8*>(slab + (mt * 16 + c) * FS + 32);
    }

    // ---- layer 1: feat @ w0 + b0, relu -> h1 (slab, stride HS) ----
    const uint4* w0q = reinterpret_cast<const uint4*>(w0p);
#pragma unroll
    for (int nt = 0; nt < 8; nt++) {
        union { uint4 q; f16x8 s; } bA, bB;
        bA.q = w0q[(nt * 2 + 0) * 64 + lane];
        bB.q = w0q[(nt * 2 + 1) * 64 + lane];
        f32x4 acc[4];
#pragma unroll
        for (int mt = 0; mt < 4; mt++) {
            f32x4 tmp = __builtin_amdgcn_mfma_f32_16x16x32_f16(a1[mt][0], bA.s, zf, 0, 0, 0);
            acc[mt]   = __builtin_amdgcn_mfma_f32_16x16x32_f16(a1[mt][1], bB.s, tmp, 0, 0, 0);
        }
        float bias = b0[nt * 16 + c];
#pragma unroll
        for (int mt = 0; mt < 4; mt++)
#pragma unroll
            for (int r = 0; r < 4; r++)
                slab[(mt * 16 + quad * 4 + r) * HS + nt * 16 + c] =
                    __float2half(fmaxf(acc[mt][r] + bias, 0.0f));
    }

    // ---- layer 2: h1 @ w1 + b1, relu -> h2 (same slab rows) ----
    f16x8 a2[4][4];
#pragma unroll
    for (int mt = 0; mt < 4; mt++)
#pragma unroll
        for (int ks = 0; ks < 4; ks++)
            a2[mt][ks] = *reinterpret_cast<const f16x8*>(
                slab + (mt * 16 + c) * HS + ks * 32 + quad * 8);

    const uint4* w1q = reinterpret_cast<const uint4*>(w1p);
#pragma unroll
    for (int nt = 0; nt < 8; nt++) {
        f32x4 acc[4] = {zf, zf, zf, zf};
#pragma unroll
        for (int ks = 0; ks < 4; ks++) {
            union { uint4 q; f16x8 s; } bb;
            bb.q = w1q[(nt * 4 + ks) * 64 + lane];
#pragma unroll
            for (int mt = 0; mt < 4; mt++)
                acc[mt] = __builtin_amdgcn_mfma_f32_16x16x32_f16(a2[mt][ks], bb.s, acc[mt], 0, 0, 0);
        }
        float bias = b1[nt * 16 + c];
#pragma unroll
        for (int mt = 0; mt < 4; mt++)
#pragma unroll
            for (int r = 0; r < 4; r++)
                slab[(mt * 16 + quad * 4 + r) * HS + nt * 16 + c] =
                    __float2half(fmaxf(acc[mt][r] + bias, 0.0f));
    }

    // ---- layer 3: h2 @ w2 (N padded to 16; cols 0..2 valid) ----
    f16x8 a3[4][4];
#pragma unroll
    for (int mt = 0; mt < 4; mt++)
#pragma unroll
        for (int ks = 0; ks < 4; ks++)
            a3[mt][ks] = *reinterpret_cast<const f16x8*>(
                slab + (mt * 16 + c) * HS + ks * 32 + quad * 8);

    const uint4* w2q = reinterpret_cast<const uint4*>(w2p);
    f32x4 acc3[4] = {zf, zf, zf, zf};
#pragma unroll
    for (int ks = 0; ks < 4; ks++) {
        union { uint4 q; f16x8 s; } bb;
        bb.q = w2q[ks * 64 + lane];
#pragma unroll
        for (int mt = 0; mt < 4; mt++)
            acc3[mt] = __builtin_amdgcn_mfma_f32_16x16x32_f16(a3[mt][ks], bb.s, acc3[mt], 0, 0, 0);
    }

    // ---- epilogue: sigmoid, weight, reduce ----
    float b2c = (c < 3) ? b2[c] : 0.0f;
    float csum = 0.0f;
#pragma unroll
    for (int mt = 0; mt < 4; mt++)
#pragma unroll
        for (int r = 0; r < 4; r++) {
            int m = wbase + mt * 16 + quad * 4 + r;
            float pre = acc3[mt][r] + b2c;
            float sg = 1.0f / (1.0f + __expf(-pre));
            csum += s_wgt[m] * sg;
        }
    csum += __shfl_xor(csum, 16);
    csum += __shfl_xor(csum, 32);
    if (quad == 0 && c < 3) atomicAdd(&s_out[c], csum);

    __syncthreads();   // barrier B
    if (t < 3) {
        float alast = s_wave[0] * s_wave[1] * s_wave[2] * s_wave[3];
        out[n * 3 + t] = s_out[t] + alast;
    }
}

// ---------- fallback (scalar fp32) if ws too small ----------
__global__ __launch_bounds__(256, 2) void dvgo_fallback(
        const float* __restrict__ pts, const float* __restrict__ viewdirs,
        const float* __restrict__ dgrid, const float* __restrict__ kgrid,
        const float* __restrict__ w0, const float* __restrict__ b0,
        const float* __restrict__ w1, const float* __restrict__ b1,
        const float* __restrict__ w2, const float* __restrict__ b2,
        float* __restrict__ out)
{
    const int n = blockIdx.x;
    const int t = threadIdx.x;
    __shared__ float s_alpha[SAMP];
    __shared__ float s_P[SAMP];
    __shared__ float s_red[12];

    const float* p = pts + ((size_t)n * SAMP + t) * 3;
    float pc[3] = {p[0], p[1], p[2]};
    int i0[3]; float fr[3];
#pragma unroll
    for (int d = 0; d < 3; d++) {
        float uu = (pc[d] + 1.0f) * 0.5f * (float)(G - 1);
        uu = fminf(fmaxf(uu, 0.0f), (float)(G - 1));
        int i = (int)floorf(uu);
        if (i > G - 2) i = G - 2;
        i0[d] = i; fr[d] = uu - (float)i;
    }
    float dens = 0.0f, k0v[CK0];
#pragma unroll
    for (int ch = 0; ch < CK0; ch++) k0v[ch] = 0.0f;
#pragma unroll
    for (int cx = 0; cx < 2; cx++)
#pragma unroll
        for (int cy = 0; cy < 2; cy++)
#pragma unroll
            for (int cz = 0; cz < 2; cz++) {
                float w = (cx ? fr[0] : 1.0f - fr[0]) * (cy ? fr[1] : 1.0f - fr[1]) * (cz ? fr[2] : 1.0f - fr[2]);
                int vidx = ((i0[0] + cx) * G + (i0[1] + cy)) * G + (i0[2] + cz);
                dens += w * dgrid[vidx];
#pragma unroll
                for (int ch = 0; ch < CK0; ch++) k0v[ch] += w * kgrid[(size_t)ch * G3 + vidx];
            }
    float xs = dens + ACT_SHIFT;
    float sp = (xs > 20.0f) ? xs : log1pf(expf(xs));
    float alpha = 1.0f - expf(-sp * 0.5f);
    s_alpha[t] = alpha; s_P[t] = 1.0f - alpha;
    __syncthreads();
#pragma unroll
    for (int off = 1; off < SAMP; off <<= 1) {
        float v = (t >= off) ? s_P[t - off] : 1.0f;
        __syncthreads();
        s_P[t] *= v;
        __syncthreads();
    }
    float v0 = viewdirs[n * 3 + 0], v1 = viewdirs[n * 3 + 1], v2 = viewdirs[n * 3 + 2];
    float inv = 1.0f / sqrtf(v0 * v0 + v1 * v1 + v2 * v2);
    v0 *= inv; v1 *= inv; v2 *= inv;
    float feat[39];
#pragma unroll
    for (int ch = 0; ch < CK0; ch++) feat[ch] = k0v[ch];
    feat[12] = v0; feat[13] = v1; feat[14] = v2;
    float vd3[3] = {v0, v1, v2};
#pragma unroll
    for (int i = 0; i < 3; i++)
#pragma unroll
        for (int j = 0; j < 4; j++) {
            float a = vd3[i] * (float)(1 << j);
            feat[15 + i * 4 + j] = sinf(a);
            feat[27 + i * 4 + j] = cosf(a);
        }
    float h1[HID];
#pragma unroll 1
    for (int ch = 0; ch < 4; ch++) {
        float acc[32];
#pragma unroll
        for (int j = 0; j < 32; j++) acc[j] = b0[ch * 32 + j];
#pragma unroll
        for (int k = 0; k < 39; k++) {
            float f = feat[k];
#pragma unroll
            for (int j = 0; j < 32; j++) acc[j] = fmaf(f, w0[k * HID + ch * 32 + j], acc[j]);
        }
#pragma unroll
        for (int j = 0; j < 32; j++) h1[ch * 32 + j] = fmaxf(acc[j], 0.0f);
    }
    float rgbpre[3] = {b2[0], b2[1], b2[2]};
#pragma unroll 1
    for (int ch = 0; ch < 4; ch++) {
        float acc[32];
#pragma unroll
        for (int j = 0; j < 32; j++) acc[j] = b1[ch * 32 + j];
#pragma unroll 4
        for (int k = 0; k < HID; k++) {
            float hk = h1[k];
#pragma unroll
            for (int j = 0; j < 32; j++) acc[j] = fmaf(hk, w1[k * HID + ch * 32 + j], acc[j]);
        }
#pragma unroll
        for (int j = 0; j < 32; j++) {
            float h2 = fmaxf(acc[j], 0.0f);
            int jj = ch * 32 + j;
            rgbpre[0] = fmaf(h2, w2[jj * 3 + 0], rgbpre[0]);
            rgbpre[1] = fmaf(h2, w2[jj * 3 + 1], rgbpre[1]);
            rgbpre[2] = fmaf(h2, w2[jj * 3 + 2], rgbpre[2]);
        }
    }
    float T_excl = (t == 0) ? 1.0f : s_P[t - 1];
    float wgt = s_alpha[t] * T_excl;
    float c0 = wgt / (1.0f + expf(-rgbpre[0]));
    float c1 = wgt / (1.0f + expf(-rgbpre[1]));
    float c2 = wgt / (1.0f + expf(-rgbpre[2]));
#pragma unroll
    for (int off = 32; off > 0; off >>= 1) {
        c0 += __shfl_down(c0, off);
        c1 += __shfl_down(c1, off);
        c2 += __shfl_down(c2, off);
    }
    if ((t & 63) == 0) {
        int wvv = t >> 6;
        s_red[wvv * 3 + 0] = c0; s_red[wvv * 3 + 1] = c1; s_red[wvv * 3 + 2] = c2;
    }
    __syncthreads();
    if (t == 0) {
        float alast = s_P[SAMP - 1];
        float o0 = alast, o1 = alast, o2 = alast;
#pragma unroll
        for (int wvv = 0; wvv < 4; wvv++) {
            o0 += s_red[wvv * 3 + 0]; o1 += s_red[wvv * 3 + 1]; o2 += s_red[wvv * 3 + 2];
        }
        out[n * 3 + 0] = o0; out[n * 3 + 1] = o1; out[n * 3 + 2] = o2;
    }
}

extern "C" void kernel_launch(void* const* d_in, const int* in_sizes, int n_in,
                              void* d_out, int out_size, void* d_ws, size_t ws_size,
                              hipStream_t stream) {
    const float* pts      = (const float*)d_in[0];
    const float* viewdirs = (const float*)d_in[1];
    const float* dgrid    = (const float*)d_in[2];
    const float* kgrid    = (const float*)d_in[3];
    const float* w0       = (const float*)d_in[4];
    const float* b0       = (const float*)d_in[5];
    const float* w1       = (const float*)d_in[6];
    const float* b1       = (const float*)d_in[7];
    const float* w2       = (const float*)d_in[8];
    const float* b2       = (const float*)d_in[9];
    float* out = (float*)d_out;

    const size_t TOTB = (size_t)(W0PE + W1PE + W2PE) * 2;   // 106,496 B

    if (ws_size >= TOTB) {
        unsigned short* w0pp = (unsigned short*)d_ws;
        unsigned short* w1pp = w0pp + W0PE;
        unsigned short* w2pp = w1pp + W1PE;
        pack_weights<<<(W0PE + W1PE + W2PE + 255) / 256, 256, 0, stream>>>(
            w0, w1, w2, w0pp, w1pp, w2pp);
        dvgo_mfma<<<NRAYS, 256, 0, stream>>>(pts, viewdirs, dgrid, kgrid,
                                             w0pp, w1pp, w2pp, b0, b1, b2, out);
    } else {
        dvgo_fallback<<<NRAYS, SAMP, 0, stream>>>(pts, viewdirs, dgrid, kgrid,
                                                  w0, b0, w1, b1, w2, b2, out);
    }
}